// Round 1
// baseline (207.023 us; speedup 1.0000x reference)
//
#include <hip/hip_runtime.h>
#include <stdint.h>

typedef __bf16 bf16x8 __attribute__((ext_vector_type(8)));
typedef float  f32x4  __attribute__((ext_vector_type(4)));

#define B_TOT 16384
#define NB    4

// ws layout (byte offsets)
#define OFF_W1T   0u         // [550][128] bf16  (w1t[(l*25+kx*5+ky)*128+oc])
#define OFF_W2B   141312u    // [128][1152] bf16 (w2b[oc][pos*128+ic])
#define OFF_FCB   436224u    // [256][128] bf16
#define OFF_WH    501760u    // [32][512] bf16 (head weights, N padded to 32)
#define OFF_BH    534528u    // [32] f32 head bias
#define OFF_SELFF 535552u    // [16384][256] bf16
#define OFF_H1    8924160u   // [16384][1152] bf16  (total ws need ~44.6 MiB)

__device__ const float d_maxv[22] = {
  9.f,1.f,1.f,10.f,3.f,254.f,1.f,1.f,235.f,8.f,
  9.f,250.f,29.f,1.f,1.f,8.f,1.f,1.f,6.f,3.f,1.f,2.f };

static __device__ __forceinline__ short f2bf(float f){
  union { float f; uint32_t u; } c; c.f = f;
  uint32_t r = (c.u + 0x7FFFu + ((c.u >> 16) & 1u)) >> 16;  // RNE
  return (short)r;
}
static __device__ __forceinline__ float bf2f(short s){
  union { uint32_t u; float f; } c; c.u = ((uint32_t)(uint16_t)s) << 16;
  return c.f;
}

// ---------------- prep: repack weights to bf16 GEMM layouts ----------------
__global__ __launch_bounds__(256) void k_prep(
    const float* __restrict__ c1w, const float* __restrict__ c2w,
    const float* __restrict__ fcw, const float* __restrict__ a0w,
    const float* __restrict__ a1w, const float* __restrict__ vw,
    const float* __restrict__ a0b, const float* __restrict__ a1b,
    const float* __restrict__ vb,
    short* __restrict__ w1t, short* __restrict__ w2b, short* __restrict__ fcb,
    short* __restrict__ wh, float* __restrict__ bh)
{
  int i = blockIdx.x * 256 + threadIdx.x;
  if (i < 70400) {                    // w1t[r*128+oc] = c1w[oc*550 + r]
    int r = i >> 7, oc = i & 127;
    w1t[i] = f2bf(c1w[oc * 550 + r]);
  }
  i -= 70400;
  if (i >= 0 && i < 147456) {         // w2b[oc*1152 + pos*128+ic] = c2w[oc][ic][pos]
    int oc = i / 1152, k = i - oc * 1152;
    int pos = k >> 7, ic = k & 127;
    w2b[i] = f2bf(c2w[oc * 1152 + ic * 9 + pos]);
  }
  i -= 147456;
  if (i >= 0 && i < 32768) fcb[i] = f2bf(fcw[i]);   // fc_w already [n][k]
  i -= 32768;
  if (i >= 0 && i < 16384) {          // wh[j*512+k], j in [0,32)
    int j = i >> 9, k = i & 511;
    float v = 0.f;
    if (j < 9) v = a0w[j * 512 + k];
    else if (j < 19) v = a1w[(j - 9) * 512 + k];
    else if (j == 19) v = vw[k];
    wh[i] = f2bf(v);
  }
  i -= 16384;
  if (i >= 0 && i < 32) {
    float v = 0.f;
    if (i < 9) v = a0b[i]; else if (i < 19) v = a1b[i - 9]; else if (i == 19) v = vb[0];
    bh[i] = v;
  }
}

// ------------- scatter + self-encoder + SPARSE conv1 (4 batches/block) -------------
__global__ __launch_bounds__(256) void k_scatter(
    const int* __restrict__ obs, const float* __restrict__ selfw,
    const float* __restrict__ selfb, const float* __restrict__ c1b,
    const short* __restrict__ w1t,
    short* __restrict__ selfF, short* __restrict__ h1)
{
  __shared__ uint32_t box[NB * 2662];   // packed (m+1)<<8 | val : last-write-wins dedup
  __shared__ float    swS[256 * 23];    // self_w staged, padded stride 23 (bank-free)
  __shared__ float    sbS[256];
  __shared__ uint32_t nzl[NB * 200];    // (cell<<8)|val winner list
  __shared__ uint32_t cnt[NB];
  __shared__ float    invS[22];

  const int tid = threadIdx.x;
  const int b0  = blockIdx.x * NB;

  for (int i = tid; i < NB * 2662; i += 256) box[i] = 0u;
  if (tid < NB) cnt[tid] = 0u;
  if (tid < 22) invS[tid] = 1.0f / (d_maxv[tid] + 1e-8f);
  for (int i = tid; i < 256 * 22; i += 256) {
    int o = i / 22, l = i - o * 22;
    swS[o * 23 + l] = selfw[i];
  }
  sbS[tid] = selfb[tid];
  __syncthreads();

  // pass 1: scatter with priority = token index m (numpy last-write-wins)
  for (int i = tid; i < NB * 200; i += 256) {
    int g = i / 200, m = i - g * 200;
    const int* p = obs + ((size_t)(b0 + g) * 200 + m) * 3;
    int c = p[0], a = p[1], v = p[2];
    c = (c == 255) ? 0 : c;  a = (a == 255) ? 0 : a;  v = (v == 255) ? 0 : v;
    int x = (c >> 4) & 15, y = c & 15;
    if (x < 11 && y < 11 && a < 22)
      atomicMax(&box[g * 2662 + a * 121 + x * 11 + y],
                ((uint32_t)(m + 1) << 8) | (uint32_t)v);
  }
  __syncthreads();

  // pass 2: winner tokens (val>0) -> nz list
  for (int i = tid; i < NB * 200; i += 256) {
    int g = i / 200, m = i - g * 200;
    const int* p = obs + ((size_t)(b0 + g) * 200 + m) * 3;
    int c = p[0], a = p[1], v = p[2];
    c = (c == 255) ? 0 : c;  a = (a == 255) ? 0 : a;  v = (v == 255) ? 0 : v;
    int x = (c >> 4) & 15, y = c & 15;
    if (x < 11 && y < 11 && a < 22 && v > 0) {
      int cell = a * 121 + x * 11 + y;
      uint32_t pack = ((uint32_t)(m + 1) << 8) | (uint32_t)v;
      if (box[g * 2662 + cell] == pack) {
        uint32_t idx = atomicAdd(&cnt[g], 1u);
        nzl[g * 200 + idx] = ((uint32_t)cell << 8) | (uint32_t)v;
      }
    }
  }

  // self encoder on center cell (box reads are broadcast; runs alongside pass 2)
  {
    const int o = tid;
    float acc0 = sbS[o], acc1 = sbS[o], acc2 = sbS[o], acc3 = sbS[o];
    #pragma unroll
    for (int l = 0; l < 22; ++l) {
      float wv = swS[o * 23 + l];
      float iv = invS[l];
      acc0 += (float)(box[0 * 2662 + l * 121 + 60] & 255u) * iv * wv;
      acc1 += (float)(box[1 * 2662 + l * 121 + 60] & 255u) * iv * wv;
      acc2 += (float)(box[2 * 2662 + l * 121 + 60] & 255u) * iv * wv;
      acc3 += (float)(box[3 * 2662 + l * 121 + 60] & 255u) * iv * wv;
    }
    selfF[(size_t)(b0 + 0) * 256 + o] = f2bf(fmaxf(acc0, 0.f));
    selfF[(size_t)(b0 + 1) * 256 + o] = f2bf(fmaxf(acc1, 0.f));
    selfF[(size_t)(b0 + 2) * 256 + o] = f2bf(fmaxf(acc2, 0.f));
    selfF[(size_t)(b0 + 3) * 256 + o] = f2bf(fmaxf(acc3, 0.f));
  }
  __syncthreads();

  // sparse conv1: ~8 nz/batch, each touches <=2x2 output positions x 128 oc
  const int oc   = tid & 127;
  const int half = tid >> 7;
  const float bias = c1b[oc];
  for (int g = half; g < NB; g += 2) {
    float acc[9];
    #pragma unroll
    for (int p = 0; p < 9; ++p) acc[p] = bias;
    const int n = (int)cnt[g];
    for (int ii = 0; ii < n; ++ii) {
      uint32_t e = nzl[g * 200 + ii];           // uniform within 128-thread group
      int v8 = (int)(e & 255u);
      int cell = (int)(e >> 8);
      int l = cell / 121, rem = cell - l * 121;
      int x = rem / 11,  y = rem - x * 11;
      float v = (float)v8 * invS[l];
      #pragma unroll
      for (int ox = 0; ox < 3; ++ox) {
        int kx = x - 3 * ox;
        if (kx < 0 || kx > 4) continue;
        #pragma unroll
        for (int oy = 0; oy < 3; ++oy) {
          int ky = y - 3 * oy;
          if (ky < 0 || ky > 4) continue;
          acc[ox * 3 + oy] += v * bf2f(w1t[(l * 25 + kx * 5 + ky) * 128 + oc]);
        }
      }
    }
    size_t base = (size_t)(b0 + g) * 1152;
    #pragma unroll
    for (int p = 0; p < 9; ++p)                  // h1[b][pos*128+oc], relu(conv1+b1)
      h1[base + p * 128 + oc] = f2bf(fmaxf(acc[p], 0.f));
  }
}

// ------------- fused conv2 -> fc -> heads GEMM chain (32 batches/block) -------------
__global__ __launch_bounds__(256, 2) void k_mlp(
    const short* __restrict__ h1, const short* __restrict__ selfF,
    const short* __restrict__ w2b, const short* __restrict__ fcb,
    const short* __restrict__ wh,  const float* __restrict__ c2b,
    const float* __restrict__ fcbias, const float* __restrict__ bh,
    float* __restrict__ out)
{
  __shared__ short h2s[32 * 128];   // XOR-swizzled (kg ^= row&7) for ds_read_b128
  __shared__ short cfs[32 * 256];

  const int tid = threadIdx.x;
  const int w   = tid >> 6;
  const int l   = tid & 63;
  const int l15 = l & 15;
  const int kg  = l >> 4;
  const int wr  = w & 1;            // 16-row half
  const int wc  = w >> 1;           // N half
  const size_t b0 = (size_t)blockIdx.x * 32;
  const f32x4 z4 = {0.f, 0.f, 0.f, 0.f};

  // ---- conv2 as GEMM: M=32 N=128 K=1152 ----
  f32x4 acc[4] = {z4, z4, z4, z4};
  const short* ap = h1 + (b0 + (size_t)(wr * 16 + l15)) * 1152 + kg * 8;
  const short* bp = w2b + (size_t)(wc * 64 + l15) * 1152 + kg * 8;
  #pragma unroll 2
  for (int kk = 0; kk < 36; ++kk) {
    bf16x8 a = *(const bf16x8*)(const void*)(ap + kk * 32);
    #pragma unroll
    for (int n = 0; n < 4; ++n) {
      bf16x8 b = *(const bf16x8*)(const void*)(bp + (size_t)n * 16 * 1152 + kk * 32);
      acc[n] = __builtin_amdgcn_mfma_f32_16x16x32_bf16(a, b, acc[n], 0, 0, 0);
    }
  }
  #pragma unroll
  for (int n = 0; n < 4; ++n) {
    int col = wc * 64 + n * 16 + l15;
    float bias = c2b[col];
    int kgc = col >> 3, c7 = col & 7;
    #pragma unroll
    for (int r = 0; r < 4; ++r) {                     // C/D: col=lane&15, row=(lane>>4)*4+r
      int row = wr * 16 + kg * 4 + r;
      float hv = fmaxf(acc[n][r] + bias, 0.f);
      h2s[row * 128 + ((kgc ^ (row & 7)) << 3) + c7] = f2bf(hv);
    }
  }
  __syncthreads();

  // ---- fc: M=32 N=256 K=128 ----
  f32x4 accf[8] = {z4, z4, z4, z4, z4, z4, z4, z4};
  const int rowA = wr * 16 + l15;
  const short* fp = fcb + (size_t)(wc * 128 + l15) * 128 + kg * 8;
  #pragma unroll 1
  for (int kk = 0; kk < 4; ++kk) {
    int kgc = kk * 4 + kg;
    bf16x8 a = *(const bf16x8*)(const void*)&h2s[rowA * 128 + ((kgc ^ (rowA & 7)) << 3)];
    #pragma unroll
    for (int n = 0; n < 8; ++n) {
      bf16x8 b = *(const bf16x8*)(const void*)(fp + (size_t)n * 16 * 128 + kk * 32);
      accf[n] = __builtin_amdgcn_mfma_f32_16x16x32_bf16(a, b, accf[n], 0, 0, 0);
    }
  }
  #pragma unroll
  for (int n = 0; n < 8; ++n) {
    int col = wc * 128 + n * 16 + l15;
    float bias = fcbias[col];
    int kgc = col >> 3, c7 = col & 7;
    #pragma unroll
    for (int r = 0; r < 4; ++r) {
      int row = wr * 16 + kg * 4 + r;
      float hv = fmaxf(accf[n][r] + bias, 0.f);
      cfs[row * 256 + ((kgc ^ (row & 7)) << 3) + c7] = f2bf(hv);
    }
  }
  __syncthreads();

  // ---- heads: M=32 N=32 K=512 (K 0..255 = selfF, 256..511 = cnn_f) ----
  f32x4 acch = z4;
  const int ncol = wc * 16 + l15;
  const short* hp = wh + (size_t)ncol * 512 + kg * 8;
  const short* sp = selfF + (b0 + (size_t)rowA) * 256 + kg * 8;
  #pragma unroll 1
  for (int kk = 0; kk < 16; ++kk) {
    bf16x8 a;
    if (kk < 8) {
      a = *(const bf16x8*)(const void*)(sp + kk * 32);
    } else {
      int kgc = (kk - 8) * 4 + kg;
      a = *(const bf16x8*)(const void*)&cfs[rowA * 256 + ((kgc ^ (rowA & 7)) << 3)];
    }
    bf16x8 b = *(const bf16x8*)(const void*)(hp + kk * 32);
    acch = __builtin_amdgcn_mfma_f32_16x16x32_bf16(a, b, acch, 0, 0, 0);
  }
  float biash = bh[ncol];
  #pragma unroll
  for (int r = 0; r < 4; ++r) {
    int row = (int)b0 + wr * 16 + kg * 4 + r;
    float v = acch[r] + biash;
    if (ncol < 9)        out[row * 9 + ncol] = v;                    // a0 [B][9]
    else if (ncol < 19)  out[147456 + row * 10 + (ncol - 9)] = v;    // a1 [B][10]
    else if (ncol == 19) out[311296 + row] = v;                      // v  [B][1]
  }
}

extern "C" void kernel_launch(void* const* d_in, const int* in_sizes, int n_in,
                              void* d_out, int out_size, void* d_ws, size_t ws_size,
                              hipStream_t stream)
{
  const int*   obs = (const int*)  d_in[0];
  const float* c1w = (const float*)d_in[1];
  const float* c1b = (const float*)d_in[2];
  const float* c2w = (const float*)d_in[3];
  const float* c2b = (const float*)d_in[4];
  const float* fcw = (const float*)d_in[5];
  const float* fcbv= (const float*)d_in[6];
  const float* sw  = (const float*)d_in[7];
  const float* sb  = (const float*)d_in[8];
  const float* a0w = (const float*)d_in[9];
  const float* a0b = (const float*)d_in[10];
  const float* a1w = (const float*)d_in[11];
  const float* a1b = (const float*)d_in[12];
  const float* vw  = (const float*)d_in[13];
  const float* vb  = (const float*)d_in[14];

  char* ws = (char*)d_ws;
  short* w1t   = (short*)(ws + OFF_W1T);
  short* w2b   = (short*)(ws + OFF_W2B);
  short* fcb   = (short*)(ws + OFF_FCB);
  short* wh    = (short*)(ws + OFF_WH);
  float* bh    = (float*)(ws + OFF_BH);
  short* selfF = (short*)(ws + OFF_SELFF);
  short* h1    = (short*)(ws + OFF_H1);
  float* out   = (float*)d_out;

  k_prep<<<dim3(1044), dim3(256), 0, stream>>>(c1w, c2w, fcw, a0w, a1w, vw,
                                               a0b, a1b, vb, w1t, w2b, fcb, wh, bh);
  k_scatter<<<dim3(B_TOT / NB), dim3(256), 0, stream>>>(obs, sw, sb, c1b, w1t, selfF, h1);
  k_mlp<<<dim3(B_TOT / 32), dim3(256), 0, stream>>>(h1, selfF, w2b, fcb, wh, c2b, fcbv, bh, out);
}

// Round 2
// 112.627 us; speedup vs baseline: 1.8381x; 1.8381x over previous
//
#include <hip/hip_runtime.h>
#include <stdint.h>

typedef __bf16 bf16x8 __attribute__((ext_vector_type(8)));
typedef float  f32x4  __attribute__((ext_vector_type(4)));

#define B_TOT 16384
#define GS    4

// ws layout (byte offsets)
#define OFF_W1T   0u         // [550][128] bf16  (w1t[(l*25+kx*5+ky)*128+oc])
#define OFF_W2B   141312u    // [128][1152] bf16 (w2b[oc][pos*128+ic])
#define OFF_FCB   436224u    // [256][128] bf16
#define OFF_WH    501760u    // [32][512] bf16 (head weights, N padded to 32)
#define OFF_BH    534528u    // [32] f32 head bias
#define OFF_SELFF 535552u    // [16384][256] bf16
#define OFF_H1    8924160u   // [16384][1152] bf16  (total ws need ~44.6 MiB)

__device__ const float d_maxv[22] = {
  9.f,1.f,1.f,10.f,3.f,254.f,1.f,1.f,235.f,8.f,
  9.f,250.f,29.f,1.f,1.f,8.f,1.f,1.f,6.f,3.f,1.f,2.f };

static __device__ __forceinline__ short f2bf(float f){
  union { float f; uint32_t u; } c; c.f = f;
  uint32_t r = (c.u + 0x7FFFu + ((c.u >> 16) & 1u)) >> 16;  // RNE
  return (short)r;
}
static __device__ __forceinline__ float bf2f(short s){
  union { uint32_t u; float f; } c; c.u = ((uint32_t)(uint16_t)s) << 16;
  return c.f;
}

// ---------------- prep: repack weights to bf16 GEMM layouts ----------------
__global__ __launch_bounds__(256) void k_prep(
    const float* __restrict__ c1w, const float* __restrict__ c2w,
    const float* __restrict__ fcw, const float* __restrict__ a0w,
    const float* __restrict__ a1w, const float* __restrict__ vw,
    const float* __restrict__ a0b, const float* __restrict__ a1b,
    const float* __restrict__ vb,
    short* __restrict__ w1t, short* __restrict__ w2b, short* __restrict__ fcb,
    short* __restrict__ wh, float* __restrict__ bh)
{
  int i = blockIdx.x * 256 + threadIdx.x;
  if (i < 70400) {                    // w1t[r*128+oc] = c1w[oc*550 + r]
    int r = i >> 7, oc = i & 127;
    w1t[i] = f2bf(c1w[oc * 550 + r]);
  }
  i -= 70400;
  if (i >= 0 && i < 147456) {         // w2b[oc*1152 + pos*128+ic] = c2w[oc][ic][pos]
    int oc = i / 1152, k = i - oc * 1152;
    int pos = k >> 7, ic = k & 127;
    w2b[i] = f2bf(c2w[oc * 1152 + ic * 9 + pos]);
  }
  i -= 147456;
  if (i >= 0 && i < 32768) fcb[i] = f2bf(fcw[i]);   // fc_w already [n][k]
  i -= 32768;
  if (i >= 0 && i < 16384) {          // wh[j*512+k], j in [0,32)
    int j = i >> 9, k = i & 511;
    float v = 0.f;
    if (j < 9) v = a0w[j * 512 + k];
    else if (j < 19) v = a1w[(j - 9) * 512 + k];
    else if (j == 19) v = vw[k];
    wh[i] = f2bf(v);
  }
  i -= 16384;
  if (i >= 0 && i < 32) {
    float v = 0.f;
    if (i < 9) v = a0b[i]; else if (i < 19) v = a1b[i - 9]; else if (i == 19) v = vb[0];
    bh[i] = v;
  }
}

// ---- scatter (sparse, no dense box) + self-encoder + sparse conv1 ----
// 1 wave per batch, GS=4 batches per 256-thread block.
__global__ __launch_bounds__(256) void k_scatter(
    const int* __restrict__ obs, const float* __restrict__ selfw,
    const float* __restrict__ selfb, const float* __restrict__ c1b,
    const short* __restrict__ w1t,
    short* __restrict__ selfF, short* __restrict__ h1)
{
  __shared__ alignas(16) int tok[GS * 600];  // staged obs tokens
  __shared__ uint32_t nzl[GS * 200];         // (m<<20)|(cell<<8)|v  valid tokens
  __shared__ uint32_t nzf[GS * 200];         // (cell<<8)|v          dedup'd winners, v>0
  __shared__ uint32_t cnt[GS], cnt2[GS];
  __shared__ float    selfv[GS * 22];        // center-cell feature per layer
  __shared__ float    invS[22];

  const int tid  = threadIdx.x;
  const int wid  = tid >> 6;
  const int lane = tid & 63;
  const int b0   = blockIdx.x * GS;
  const int b    = b0 + wid;

  if (tid < GS) { cnt[tid] = 0u; cnt2[tid] = 0u; }
  if (tid < 22) invS[tid] = 1.0f / (d_maxv[tid] + 1e-8f);
  for (int i = tid; i < GS * 22; i += 256) selfv[i] = 0.f;

  // stage obs: GS*600 ints contiguous, coalesced int4 loads
  {
    const int4* src = (const int4*)(obs + (size_t)b0 * 600);
    int4* dst = (int4*)tok;
    for (int i = tid; i < GS * 150; i += 256) dst[i] = src[i];
  }
  __syncthreads();

  // parse: wave wid handles batch wid; append valid tokens
  for (int m = lane; m < 200; m += 64) {
    int c = tok[wid * 600 + m * 3];
    int a = tok[wid * 600 + m * 3 + 1];
    int v = tok[wid * 600 + m * 3 + 2];
    c = (c == 255) ? 0 : c;  a = (a == 255) ? 0 : a;  v = (v == 255) ? 0 : v;
    int x = (c >> 4) & 15, y = c & 15;
    if (x < 11 && y < 11 && a < 22) {
      uint32_t cell = (uint32_t)(a * 121 + x * 11 + y);
      uint32_t idx = atomicAdd(&cnt[wid], 1u);
      nzl[wid * 200 + idx] = ((uint32_t)m << 20) | (cell << 8) | (uint32_t)v;
    }
  }
  __syncthreads();

  // dedup (last-write-wins = max m per cell), compact survivors with v>0,
  // and extract center-cell values for the self encoder
  {
    const uint32_t n = cnt[wid];
    for (uint32_t i = lane; i < n; i += 64) {
      uint32_t e = nzl[wid * 200 + i];
      uint32_t cell = (e >> 8) & 0xFFFu;
      bool winner = true;
      for (uint32_t j = 0; j < n; ++j) {
        uint32_t ej = nzl[wid * 200 + j];
        if (((ej >> 8) & 0xFFFu) == cell && ej > e) { winner = false; break; }
      }
      if (winner && (e & 255u) != 0u) {
        uint32_t id2 = atomicAdd(&cnt2[wid], 1u);
        nzf[wid * 200 + id2] = e & 0xFFFFFu;
        uint32_t l = cell / 121u;
        if (cell - l * 121u == 60u)                 // x=5,y=5
          selfv[wid * 22 + l] = (float)(e & 255u) * invS[l];
      }
    }
  }
  __syncthreads();

  // self encoder: wave wid -> batch wid; lane owns outputs 4*lane..4*lane+3
  {
    const int o0 = lane * 4;
    float acc[4];
    #pragma unroll
    for (int j = 0; j < 4; ++j) acc[j] = selfb[o0 + j];
    #pragma unroll
    for (int l = 0; l < 22; ++l) {
      float sv = selfv[wid * 22 + l];               // broadcast
      #pragma unroll
      for (int j = 0; j < 4; ++j)
        acc[j] += sv * selfw[(o0 + j) * 22 + l];
    }
    union { uint32_t u[2]; } pk;
    pk.u[0] = (uint32_t)(uint16_t)f2bf(fmaxf(acc[0], 0.f))
            | ((uint32_t)(uint16_t)f2bf(fmaxf(acc[1], 0.f)) << 16);
    pk.u[1] = (uint32_t)(uint16_t)f2bf(fmaxf(acc[2], 0.f))
            | ((uint32_t)(uint16_t)f2bf(fmaxf(acc[3], 0.f)) << 16);
    uint32_t* dst = (uint32_t*)(selfF + (size_t)b * 256 + o0);
    dst[0] = pk.u[0]; dst[1] = pk.u[1];
  }

  // sparse conv1: wave wid -> batch wid; lane owns oc = 2*lane, 2*lane+1
  {
    const int oc0 = lane * 2;
    float acc[9][2];
    const float bz0 = c1b[oc0], bz1 = c1b[oc0 + 1];
    #pragma unroll
    for (int p = 0; p < 9; ++p) { acc[p][0] = bz0; acc[p][1] = bz1; }
    const int n2 = (int)cnt2[wid];
    for (int ii = 0; ii < n2; ++ii) {
      uint32_t e = nzf[wid * 200 + ii];             // broadcast
      int v8 = (int)(e & 255u);
      int cell = (int)(e >> 8);
      int l = cell / 121, rem = cell - l * 121;
      int x = rem / 11,  y = rem - x * 11;
      float v = (float)v8 * invS[l];
      #pragma unroll
      for (int ox = 0; ox < 3; ++ox) {
        int kx = x - 3 * ox;
        if (kx < 0 || kx > 4) continue;
        #pragma unroll
        for (int oy = 0; oy < 3; ++oy) {
          int ky = y - 3 * oy;
          if (ky < 0 || ky > 4) continue;
          uint32_t wp = *(const uint32_t*)(const void*)
                        &w1t[(l * 25 + kx * 5 + ky) * 128 + oc0];
          acc[ox * 3 + oy][0] += v * bf2f((short)(wp & 0xFFFFu));
          acc[ox * 3 + oy][1] += v * bf2f((short)(wp >> 16));
        }
      }
    }
    uint32_t* dst = (uint32_t*)h1 + (size_t)b * 576 + lane;
    #pragma unroll
    for (int p = 0; p < 9; ++p) {
      uint32_t pk = (uint32_t)(uint16_t)f2bf(fmaxf(acc[p][0], 0.f))
                  | ((uint32_t)(uint16_t)f2bf(fmaxf(acc[p][1], 0.f)) << 16);
      dst[p * 64] = pk;
    }
  }
}

// ------------- fused conv2 -> fc -> heads GEMM chain (32 batches/block) -------------
__global__ __launch_bounds__(256, 2) void k_mlp(
    const short* __restrict__ h1, const short* __restrict__ selfF,
    const short* __restrict__ w2b, const short* __restrict__ fcb,
    const short* __restrict__ wh,  const float* __restrict__ c2b,
    const float* __restrict__ fcbias, const float* __restrict__ bh,
    float* __restrict__ out)
{
  __shared__ short h2s[32 * 128];   // XOR-swizzled (kg ^= row&7) for ds_read_b128
  __shared__ short cfs[32 * 256];

  const int tid = threadIdx.x;
  const int w   = tid >> 6;
  const int l   = tid & 63;
  const int l15 = l & 15;
  const int kg  = l >> 4;
  const int wr  = w & 1;            // 16-row half
  const int wc  = w >> 1;           // N half
  const size_t b0 = (size_t)blockIdx.x * 32;
  const f32x4 z4 = {0.f, 0.f, 0.f, 0.f};

  // ---- conv2 as GEMM: M=32 N=128 K=1152 ----
  f32x4 acc[4] = {z4, z4, z4, z4};
  const short* ap = h1 + (b0 + (size_t)(wr * 16 + l15)) * 1152 + kg * 8;
  const short* bp = w2b + (size_t)(wc * 64 + l15) * 1152 + kg * 8;
  #pragma unroll 2
  for (int kk = 0; kk < 36; ++kk) {
    bf16x8 a = *(const bf16x8*)(const void*)(ap + kk * 32);
    #pragma unroll
    for (int n = 0; n < 4; ++n) {
      bf16x8 b = *(const bf16x8*)(const void*)(bp + (size_t)n * 16 * 1152 + kk * 32);
      acc[n] = __builtin_amdgcn_mfma_f32_16x16x32_bf16(a, b, acc[n], 0, 0, 0);
    }
  }
  #pragma unroll
  for (int n = 0; n < 4; ++n) {
    int col = wc * 64 + n * 16 + l15;
    float bias = c2b[col];
    int kgc = col >> 3, c7 = col & 7;
    #pragma unroll
    for (int r = 0; r < 4; ++r) {                     // C/D: col=lane&15, row=(lane>>4)*4+r
      int row = wr * 16 + kg * 4 + r;
      float hv = fmaxf(acc[n][r] + bias, 0.f);
      h2s[row * 128 + ((kgc ^ (row & 7)) << 3) + c7] = f2bf(hv);
    }
  }
  __syncthreads();

  // ---- fc: M=32 N=256 K=128 ----
  f32x4 accf[8] = {z4, z4, z4, z4, z4, z4, z4, z4};
  const int rowA = wr * 16 + l15;
  const short* fp = fcb + (size_t)(wc * 128 + l15) * 128 + kg * 8;
  #pragma unroll 1
  for (int kk = 0; kk < 4; ++kk) {
    int kgc = kk * 4 + kg;
    bf16x8 a = *(const bf16x8*)(const void*)&h2s[rowA * 128 + ((kgc ^ (rowA & 7)) << 3)];
    #pragma unroll
    for (int n = 0; n < 8; ++n) {
      bf16x8 b = *(const bf16x8*)(const void*)(fp + (size_t)n * 16 * 128 + kk * 32);
      accf[n] = __builtin_amdgcn_mfma_f32_16x16x32_bf16(a, b, accf[n], 0, 0, 0);
    }
  }
  #pragma unroll
  for (int n = 0; n < 8; ++n) {
    int col = wc * 128 + n * 16 + l15;
    float bias = fcbias[col];
    int kgc = col >> 3, c7 = col & 7;
    #pragma unroll
    for (int r = 0; r < 4; ++r) {
      int row = wr * 16 + kg * 4 + r;
      float hv = fmaxf(accf[n][r] + bias, 0.f);
      cfs[row * 256 + ((kgc ^ (row & 7)) << 3) + c7] = f2bf(hv);
    }
  }
  __syncthreads();

  // ---- heads: M=32 N=32 K=512 (K 0..255 = selfF, 256..511 = cnn_f) ----
  f32x4 acch = z4;
  const int ncol = wc * 16 + l15;
  const short* hp = wh + (size_t)ncol * 512 + kg * 8;
  const short* sp = selfF + (b0 + (size_t)rowA) * 256 + kg * 8;
  #pragma unroll 1
  for (int kk = 0; kk < 16; ++kk) {
    bf16x8 a;
    if (kk < 8) {
      a = *(const bf16x8*)(const void*)(sp + kk * 32);
    } else {
      int kgc = (kk - 8) * 4 + kg;
      a = *(const bf16x8*)(const void*)&cfs[rowA * 256 + ((kgc ^ (rowA & 7)) << 3)];
    }
    bf16x8 b = *(const bf16x8*)(const void*)(hp + kk * 32);
    acch = __builtin_amdgcn_mfma_f32_16x16x32_bf16(a, b, acch, 0, 0, 0);
  }
  float biash = bh[ncol];
  #pragma unroll
  for (int r = 0; r < 4; ++r) {
    int row = (int)b0 + wr * 16 + kg * 4 + r;
    float v = acch[r] + biash;
    if (ncol < 9)        out[row * 9 + ncol] = v;                    // a0 [B][9]
    else if (ncol < 19)  out[147456 + row * 10 + (ncol - 9)] = v;    // a1 [B][10]
    else if (ncol == 19) out[311296 + row] = v;                      // v  [B][1]
  }
}

extern "C" void kernel_launch(void* const* d_in, const int* in_sizes, int n_in,
                              void* d_out, int out_size, void* d_ws, size_t ws_size,
                              hipStream_t stream)
{
  const int*   obs = (const int*)  d_in[0];
  const float* c1w = (const float*)d_in[1];
  const float* c1b = (const float*)d_in[2];
  const float* c2w = (const float*)d_in[3];
  const float* c2b = (const float*)d_in[4];
  const float* fcw = (const float*)d_in[5];
  const float* fcbv= (const float*)d_in[6];
  const float* sw  = (const float*)d_in[7];
  const float* sb  = (const float*)d_in[8];
  const float* a0w = (const float*)d_in[9];
  const float* a0b = (const float*)d_in[10];
  const float* a1w = (const float*)d_in[11];
  const float* a1b = (const float*)d_in[12];
  const float* vw  = (const float*)d_in[13];
  const float* vb  = (const float*)d_in[14];

  char* ws = (char*)d_ws;
  short* w1t   = (short*)(ws + OFF_W1T);
  short* w2b   = (short*)(ws + OFF_W2B);
  short* fcb   = (short*)(ws + OFF_FCB);
  short* wh    = (short*)(ws + OFF_WH);
  float* bh    = (float*)(ws + OFF_BH);
  short* selfF = (short*)(ws + OFF_SELFF);
  short* h1    = (short*)(ws + OFF_H1);
  float* out   = (float*)d_out;

  k_prep<<<dim3(1044), dim3(256), 0, stream>>>(c1w, c2w, fcw, a0w, a1w, vw,
                                               a0b, a1b, vb, w1t, w2b, fcb, wh, bh);
  k_scatter<<<dim3(B_TOT / GS), dim3(256), 0, stream>>>(obs, sw, sb, c1b, w1t, selfF, h1);
  k_mlp<<<dim3(B_TOT / 32), dim3(256), 0, stream>>>(h1, selfF, w2b, fcb, wh, c2b, fcbv, bh, out);
}